// Round 5
// baseline (136.991 us; speedup 1.0000x reference)
//
#include <hip/hip_runtime.h>
#include <hip/hip_bf16.h>

// SSIM loss, round 12: PAGE-LOCAL block-cooperative staging.
// r7/r10/r11 all capped at ~1 TB/s regardless of staging mechanism (regs vs
// LDS-DMA), row-coalescing, or pipeline depth. Shared invariant: every
// staging inst scattered 64 lanes across 8-16 rows 2KB apart = 4-8 distinct
// 4KB pages PER INSTRUCTION -> serialized address-translation (UTCL1 walk)
// throttles issue; queues fill; latency balloons to ~4us (measured 9.9k-cyc
// stalls). m13's 6.3 TB/s copy touches 1 page/inst.
// Fix: each global_load_lds covers 2 adjacent rows x 512B = ONE aligned 4KB
// page. Window must be 128 cols wide -> the block's 4 waves (adjacent 16-col
// stripes = 64-col super-stripe) stage cooperatively into a shared buffer:
// 16 insts/tile (8 row-pairs x 2 tensors), 4 per wave. Global source is
// XOR-swizzled (granule ^ row&7) so LDS stays linear (m173) and read-back is
// bank-clean. Cross-wave handoff: own-wave counted vmcnt + RAW s_barrier
// (no compiler vmcnt(0) drain -- m201 pattern). hring/vstep/SSIM unchanged.

typedef float  f32x4  __attribute__((ext_vector_type(4)));
typedef short  short8 __attribute__((ext_vector_type(8)));
typedef short  short4v __attribute__((ext_vector_type(4)));

#define NBLOCK 512    // 2 blk/CU (69.6 KB LDS) -> whole grid resident

__device__ __forceinline__ short bf16s(float x) {
    __hip_bfloat16 h = __float2bfloat16(x);
    return __builtin_bit_cast(short, h);
}
__device__ __forceinline__ float bf16f(float x) {
    unsigned u = (unsigned)__builtin_bit_cast(unsigned short,
                                              __float2bfloat16(x)) << 16;
    return __builtin_bit_cast(float, u);
}
__device__ __forceinline__ void gload16(const float* g, float* lds) {
    __builtin_amdgcn_global_load_lds(g, lds, 16, 0, 0);
}

#define WAIT4 asm volatile("s_waitcnt vmcnt(4)" ::: "memory")
#define WAIT0 asm volatile("s_waitcnt vmcnt(0)" ::: "memory")
#define LGK0  asm volatile("s_waitcnt lgkmcnt(0)" ::: "memory")
#define BAR   __builtin_amdgcn_s_barrier()

__global__ __launch_bounds__(256, 2)
void ssim_main(const float* __restrict__ pred, const float* __restrict__ targ,
               float* __restrict__ slotSum, unsigned int* __restrict__ grpCnt,
               unsigned int* __restrict__ finalCnt, float* __restrict__ out) {
    const float W[11] = {
        0.00102840f, 0.00759876f, 0.03600077f, 0.10936070f, 0.21300554f,
        0.26601173f,
        0.21300554f, 0.10936070f, 0.03600077f, 0.00759876f, 0.00102840f};

    __shared__ __align__(16) short hring[4][4][16][72];   // 36,864 B
    __shared__ float wsum[4];
    extern __shared__ __align__(16) float raw[];          // [2][2][16][128] f32

    const int w     = threadIdx.x >> 6;
    const int L     = threadIdx.x & 63;
    const int n     = L & 15;
    const int quad  = L >> 4;
    const int b     = blockIdx.x;
    const int img   = b >> 4;                // 32 images x 16 blocks
    const int rem   = b & 15;
    const int q     = rem >> 3;              // half-image strip (16 tiles)
    const int sst   = rem & 7;               // 64-col super-stripe
    const int C0    = sst << 6;
    const int c0    = C0 + (w << 4);         // this wave's output stripe
    const int s0    = q << 4;
    const bool edge = (c0 == 0) | (c0 == 496);

    const float* __restrict__ pim = pred + (size_t)img * 262144;
    const float* __restrict__ tim = targ + (size_t)img * 262144;

    float S = 0.f;
#pragma unroll
    for (int kk = 0; kk < 11; ++kk) S += bf16f(W[kk]);
    const float c2 = 1.0f / (S * S);

    short8 bw;
#pragma unroll
    for (int j = 0; j < 8; ++j) {
        const int d = quad * 8 + j - n - 3;
        bw[j] = bf16s((d >= 0 && d <= 10) ? W[d] : 0.f);
    }
    const f32x4 zc = {0.f, 0.f, 0.f, 0.f};

    // ---- staging lane constants (page-local, XOR-swizzled source) ----
    // wave role: tensor tsel = w>>1, row-pairs pbase..pbase+3 (pbase=(w&1)*4).
    // inst j covers rows 2(pbase+j), +1 x cols [C0-32, C0+96): 2 rows x 512B
    // = one aligned 4KB page (rows 2k,2k+1 share a page; image base aligned).
    const int tsel  = w >> 1;
    const int pbase = (w & 1) * 4;
    const float* __restrict__ imw = tsel ? tim : pim;
    int rho_[4], col_[4];
#pragma unroll
    for (int j = 0; j < 4; ++j) {
        const int rho = 2 * (pbase + j) + (L >> 5);       // row in tile 0..15
        const int gs  = (L & 31) ^ ((2 * j + (L >> 5)) & 7); // src granule
        rho_[j] = rho;
        col_[j] = min(max(C0 - 32 + 4 * gs, 0), 508);     // clamped col
    }

    // ---- read-side lane constants (un-permute) ----
    // lane (n,quad) wants src granules gA0=6+4w+2q, +1 of row n; stored at
    // granule g ^ (n&7). Bank check: (g%8)^(n&7) spans all 8 -> all 32 banks.
    const int gA = (6 + 4 * w + 2 * quad) ^ (n & 7);
    const int gB = (7 + 4 * w + 2 * quad) ^ (n & 7);
    const int cb = c0 - 8 + quad * 8;
    const bool ok0 = (unsigned)cb < 512u;
    const bool ok1 = (unsigned)(cb + 4) < 512u;

    float lsum = 0.f;

    // ---- issue this wave's 4 page-local loads for tile Ts, slot Ts&1 ----
    auto issue = [&](int Ts) {
        const int slot = Ts & 1;
        float* dbase = raw + slot * 4096 + tsel * 2048 + 2 * pbase * 128;
#pragma unroll
        for (int j = 0; j < 4; ++j) {
            const int grow = min(max(16 * Ts + rho_[j], 0), 511);
            gload16(imw + grow * 512 + col_[j], dbase + j * 256);
        }
    };

    // ---- read slot, cvt + hblur MFMA + ring store (caller synced) ----
    auto hproc = [&](int Tt) {
        const int wslot = ((Tt << 4) & 63) + quad * 4;
        short4v o[4];
        if ((unsigned)Tt > 31u) {
#pragma unroll
            for (int f = 0; f < 4; ++f) o[f] = (short4v){0, 0, 0, 0};
        } else {
            const float* bp = raw + (Tt & 1) * 4096 + n * 128;
            const float* bt = bp + 2048;
            f32x4 p0 = *(const f32x4*)(bp + gA * 4);
            f32x4 p1 = *(const f32x4*)(bp + gB * 4);
            f32x4 t0 = *(const f32x4*)(bt + gA * 4);
            f32x4 t1 = *(const f32x4*)(bt + gB * 4);
            if (edge) {            // wave-uniform branch, per-lane masks
                p0 = ok0 ? p0 : zc;  p1 = ok1 ? p1 : zc;
                t0 = ok0 ? t0 : zc;  t1 = ok1 ? t1 : zc;
            }
            short8 fa[4];
#pragma unroll
            for (int j = 0; j < 4; ++j) {
                const float pj = p0[j], tj = t0[j];
                const float u = pj + tj, v = pj - tj;
                fa[0][j] = bf16s(pj);
                fa[1][j] = bf16s(tj);
                fa[2][j] = bf16s(u * u);
                fa[3][j] = bf16s(v * v);
            }
#pragma unroll
            for (int j = 0; j < 4; ++j) {
                const float pj = p1[j], tj = t1[j];
                const float u = pj + tj, v = pj - tj;
                fa[0][j + 4] = bf16s(pj);
                fa[1][j + 4] = bf16s(tj);
                fa[2][j + 4] = bf16s(u * u);
                fa[3][j + 4] = bf16s(v * v);
            }
#pragma unroll
            for (int f = 0; f < 4; ++f) {
                const f32x4 d = __builtin_amdgcn_mfma_f32_16x16x32_bf16(
                    fa[f], bw, zc, 0, 0, 0);
                short4v ov;
#pragma unroll
                for (int r2 = 0; r2 < 4; ++r2) ov[r2] = bf16s(d[r2]);
                o[f] = ov;
            }
        }
#pragma unroll
        for (int f = 0; f < 4; ++f)
            *(short4v*)&hring[w][f][n][wslot] = o[f];
    };

    // ---- vblur MFMA + SSIM math for output tile s ----
    auto vstep = [&](int s) {
        const int rslot0 = (int)(((unsigned)((s << 4) - 8)) & 63u);
        const int chunk  = (rslot0 + quad * 8) & 63;
        f32x4 dv[4];
#pragma unroll
        for (int f = 0; f < 4; ++f) {
            const short8 af = *(const short8*)&hring[w][f][n][chunk];
            dv[f] = __builtin_amdgcn_mfma_f32_16x16x32_bf16(af, bw, zc, 0, 0, 0);
        }
#pragma unroll
        for (int r = 0; r < 4; ++r) {
            const float m1 = dv[0][r] * c2, m2 = dv[1][r] * c2;
            const float Av = dv[2][r] * c2, Bv = dv[3][r] * c2;
            const float m12  = m1 * m2;
            const float smsq = m1 * m1 + m2 * m2;
            const float s12  = __builtin_fmaf(0.25f, Av - Bv, -m12);
            const float s1s2 = __builtin_fmaf(0.5f,  Av + Bv, -smsq);
            const float num = __builtin_fmaf(2.f, m12, 1e-4f) *
                              __builtin_fmaf(2.f, s12, 9e-4f);
            const float den = (smsq + 1e-4f) * (s1s2 + 9e-4f);
            float rc = __builtin_amdgcn_rcpf(den);
            rc = rc * (2.f - den * rc);
            lsum = __builtin_fmaf(num, rc, lsum);
        }
    };

    // ---- prologue: hprocs s0-1..s0+1; leaves s0+3 in flight ----
    issue(s0 - 1); issue(s0);
    WAIT4; BAR; hproc(s0 - 1);
    LGK0;  BAR; issue(s0 + 1);
    WAIT4; BAR; hproc(s0);
    LGK0;  BAR; issue(s0 + 2);
    WAIT4; BAR; hproc(s0 + 1);
    LGK0;  BAR; issue(s0 + 3);

    // ---- 15 steps; own-wave counted vmcnt keeps next tile in flight ----
#pragma unroll 1
    for (int s = s0; s < s0 + 15; ++s) {
        vstep(s);
        if (s <= s0 + 13) { WAIT4; } else { WAIT0; }
        BAR;                         // tile s+2 fully in LDS (all waves)
        hproc(s + 2);
        LGK0; BAR;                   // slot (s+2)&1 free to overwrite
        if (s + 4 <= s0 + 16) issue(s + 4);
    }
    vstep(s0 + 15);

    // ---- hierarchical reduce ----
#pragma unroll
    for (int off = 32; off > 0; off >>= 1)
        lsum += __shfl_down(lsum, off, 64);
    if (L == 0) wsum[w] = lsum;
    __syncthreads();
    if (threadIdx.x == 0) {
        const float bs = wsum[0] + wsum[1] + wsum[2] + wsum[3];
        const int g = blockIdx.x & 63;           // 64 groups x 8 blocks
        atomicAdd(&slotSum[g * 16], bs);         // slots 64 B apart
        __threadfence();
        if (atomicAdd(&grpCnt[g * 16], 1u) == 7u) {
            __threadfence();
            if (atomicAdd(finalCnt, 1u) == 63u) {
                float s = 0.f;
#pragma unroll
                for (int i = 0; i < 64; ++i)
                    s += atomicAdd(&slotSum[i * 16], 0.f);  // coherent reads
                out[0] = 1.0f - s * (1.0f / 8388608.0f);
            }
        }
    }
}

extern "C" void kernel_launch(void* const* d_in, const int* in_sizes, int n_in,
                              void* d_out, int out_size, void* d_ws,
                              size_t ws_size, hipStream_t stream) {
    const float* pred = (const float*)d_in[0];
    const float* targ = (const float*)d_in[1];
    // ws layout: [0,4096) slotSum[64] @64B stride; [4096,8192) grpCnt[64]
    //            @64B stride; [8192,8196) finalCnt
    float* slotSum = (float*)d_ws;
    unsigned int* grpCnt = (unsigned int*)((char*)d_ws + 4096);
    unsigned int* finalCnt = (unsigned int*)((char*)d_ws + 8192);

    hipMemsetAsync(d_ws, 0, 8196, stream);
    ssim_main<<<dim3(NBLOCK), dim3(256), 32768, stream>>>(pred, targ, slotSum,
                                                          grpCnt, finalCnt,
                                                          (float*)d_out);
    (void)in_sizes; (void)n_in; (void)out_size; (void)ws_size;
}